// Round 3
// baseline (83.670 us; speedup 1.0000x reference)
//
#include <hip/hip_runtime.h>

// Problem geometry (fixed by setup_inputs):
//   img: (1080, 1920, 3) fp32; x = img[3:-3] -> (1074, 1920, 3)
//   vertical median, window 5, symmetric padding along axis 0.
//
// R7 theory: kernel is HBM-traffic-proportional (R5: +38 MB extra reads ->
// +5.7 µs = HBM marginal rate; R6: MLP restructure neutral). Remaining
// excess = halo re-reads across strip boundaries (~17 MB at RPB=6).
// Fix: bijective XCD-chunked block swizzle (T1/m204) so vertically-adjacent
// strips run on the SAME XCD -> halo rows re-read from that XCD's 4 MB L2
// (re-use distance ~6 blocks ≈ 288 KB) instead of HBM.
//   - 1-D grid of 1074 blocks; HW round-robins orig id across 8 XCDs.
//   - newlin gives each XCD a contiguous chunk of (x,y) work space,
//     x fastest -> strip y and y+1 are 6 blocks apart on one XCD.
// Keep R6's straight-line RPB=6 body (1074 = 179*6 exact, no tail).
#define N_ROWS 1074          // output rows
#define ROW_V4 1440          // float4 per row (1920*3/4)
#define RPB    6             // output rows per thread (exact: 179 strips)
#define NLD    (RPB + 4)     // window rows loaded per thread
#define XCHUNKS 6            // ceil(1440/256)
#define NWG    (XCHUNKS * (N_ROWS / RPB))   // 1074 workgroups
#define NXCD   8

__device__ __forceinline__ void cswap(float& a, float& b) {
    float lo = fminf(a, b);
    b = fmaxf(a, b);
    a = lo;
}

// Devillard opt_med5: 7 compare-exchanges, result in p2.
__device__ __forceinline__ float med5(float p0, float p1, float p2, float p3, float p4) {
    cswap(p0, p1); cswap(p3, p4); cswap(p0, p3);
    cswap(p1, p4); cswap(p1, p2); cswap(p2, p3);
    cswap(p1, p2);
    return p2;
}

__device__ __forceinline__ float4 med5v(const float4& a, const float4& b,
                                        const float4& c, const float4& d,
                                        const float4& e) {
    float4 r;
    r.x = med5(a.x, b.x, c.x, d.x, e.x);
    r.y = med5(a.y, b.y, c.y, d.y, e.y);
    r.z = med5(a.z, b.z, c.z, d.z, e.z);
    r.w = med5(a.w, b.w, c.w, d.w, e.w);
    return r;
}

__global__ __launch_bounds__(256)
void VerticalMedian_54262616818099_kernel(const float* __restrict__ img,
                                          float* __restrict__ out) {
    // Bijective XCD-chunked swizzle (m204 variant): orig%8 ~ XCD.
    // q=134, r=2 for NWG=1074 -> XCDs 0,1 get 135 blocks, 2..7 get 134.
    const int orig = blockIdx.x;
    const int xcd  = orig % NXCD;
    const int idx  = orig / NXCD;
    const int q    = NWG / NXCD;            // 134
    const int r    = NWG % NXCD;            // 2
    const int newlin = (xcd < r ? xcd * (q + 1)
                                : r * (q + 1) + (xcd - r) * q) + idx;
    const int bx = newlin % XCHUNKS;        // column chunk (fast dim)
    const int by = newlin / XCHUNKS;        // row strip

    const int c4 = bx * 256 + threadIdx.x;  // float4 column index
    if (c4 >= ROW_V4) return;               // last x-chunk partial (1536>1440)
    const int i0 = by * RPB;                // first output row of strip

    const float4* __restrict__ in4 = (const float4*)img + c4;
    float4* __restrict__ o4 = (float4*)out + c4;

    // Issue ALL window-row loads before any use (R6 structure, proven
    // neutral-vs-baseline; kept for its straight-line simplicity).
    float4 w[NLD];
#pragma unroll
    for (int k = 0; k < NLD; ++k) {
        int j = i0 + k - 2;
        j = (j < 0) ? (-1 - j) : j;                    // symmetric reflect top
        j = (j >= N_ROWS) ? (2 * N_ROWS - 1 - j) : j;  // symmetric reflect bottom
        w[k] = in4[(size_t)(j + 3) * ROW_V4];          // +3 crops img[3:-3]
    }

#pragma unroll
    for (int r2 = 0; r2 < RPB; ++r2) {
        o4[(size_t)(i0 + r2) * ROW_V4] =
            med5v(w[r2], w[r2 + 1], w[r2 + 2], w[r2 + 3], w[r2 + 4]);
    }
}

extern "C" void kernel_launch(void* const* d_in, const int* in_sizes, int n_in,
                              void* d_out, int out_size, void* d_ws, size_t ws_size,
                              hipStream_t stream) {
    const float* img = (const float*)d_in[0];
    // d_in[1] = mask (unused by reference output), d_in[2] = vertical_size (fixed 5)
    float* out = (float*)d_out;

    dim3 block(256, 1, 1);
    dim3 grid(NWG, 1, 1);                   // 1-D so orig id -> XCD mapping is explicit
    VerticalMedian_54262616818099_kernel<<<grid, block, 0, stream>>>(img, out);
}